// Round 25
// baseline (241.959 us; speedup 1.0000x reference)
//
#include <hip/hip_runtime.h>
#include <cstdint>

#define EPSV 1e-5f
#define AS1 __attribute__((address_space(1)))
#define AS3 __attribute__((address_space(3)))

#define VMCNT_BAR(N) do { \
    asm volatile("s_waitcnt vmcnt(" #N ") lgkmcnt(0)" ::: "memory"); \
    __builtin_amdgcn_sched_barrier(0); \
    __builtin_amdgcn_s_barrier(); } while (0)

typedef __attribute__((ext_vector_type(8))) short short8v;   // 8 bf16
typedef __attribute__((ext_vector_type(4))) float float4v;

__device__ inline unsigned short f2bf(float f) {
    union { float f; unsigned int u; } v; v.f = f;
    unsigned int r = v.u + 0x7FFF + ((v.u >> 16) & 1);
    return (unsigned short)(r >> 16);
}

// Chunked B layout: per 32-wide K-step a 16KB chunk in MFMA-fragment order.
__device__ inline size_t bidx(int n, int k) {
    return ((size_t)(k >> 5) << 13) + ((size_t)(n >> 4) << 9)
         + (((k >> 3) & 3) << 7) + ((n & 15) << 3) + (k & 7);
}

__device__ inline void gld16(const unsigned short* g, unsigned short* d) {
    __builtin_amdgcn_global_load_lds((const AS1 void*)g, (AS3 void*)d, 16, 0, 0);
}

// 256-thread form: one wave fills its share of chunk s (8192 elems)
__device__ inline void issue_b(const unsigned short* Bc, int s, unsigned short* bsb,
                               int w, int l) {
    const unsigned short* g = Bc + ((size_t)s << 13) + (w << 9) + (l << 3);
    unsigned short* d = bsb + (w << 9) + (l << 3);
    #pragma unroll
    for (int i = 0; i < 4; ++i)
        gld16(g + (i << 11), d + (i << 11));
}

// 512-thread form: 8 waves fill chunk-pair (2s, 2s+1) = 32KB into bsb[16384]
__device__ inline void issue_b8(const unsigned short* Bc, int s, unsigned short* bsb,
                                int w, int l) {
    const unsigned short* g = Bc + ((size_t)(2 * s) << 13);
    #pragma unroll
    for (int i = 0; i < 4; ++i) {
        int blk = (w + i * 8) << 9;
        gld16(g + blk + (l << 3), bsb + blk + (l << 3));
    }
}

// ===========================================================================
// prep1: wt_all (bid 0..255) + bn_stats (256..511) + mask_sniff (512..623)
//        + build_maps (624, 256-thread scan). Uniform per-block branch.
// ===========================================================================
__global__ __launch_bounds__(256) void prep1_k(
    const float* __restrict__ contp, float* __restrict__ stats,
    const unsigned char* __restrict__ msrc, int* __restrict__ flags,
    const int* __restrict__ qidx, int* __restrict__ kmap,
    const float* __restrict__ nW, const float* __restrict__ cW, const float* __restrict__ mW,
    const float* __restrict__ qW, const float* __restrict__ kW, const float* __restrict__ vW,
    const float* __restrict__ r1W, const float* __restrict__ r2W,
    unsigned short* __restrict__ nO, unsigned short* __restrict__ cO, unsigned short* __restrict__ mO,
    unsigned short* __restrict__ qO, unsigned short* __restrict__ kO, unsigned short* __restrict__ vO,
    unsigned short* __restrict__ r1O, unsigned short* __restrict__ r2O)
{
    __shared__ float T[64][65];
    __shared__ float ss[8], sq[8];
    __shared__ int flag[1024];
    __shared__ int psc[256];
    const int bid = blockIdx.x;
    const int tid = threadIdx.x;

    if (bid < 256) {
        const float* W; unsigned short* O; int K, tile;
        if (bid < 64)       { W = nW; O = nO; K = 1024; tile = bid; }
        else if (bid < 128) { W = cW; O = cO; K = 1024; tile = bid - 64; }
        else if (bid < 176) { W = mW; O = mO; K = 768;  tile = bid - 128; }
        else {
            int s = (bid - 176) >> 4; tile = (bid - 176) & 15; K = 256;
            switch (s) {
                case 0: W = qW;  O = qO;  break;
                case 1: W = kW;  O = kO;  break;
                case 2: W = vW;  O = vO;  break;
                case 3: W = r1W; O = r1O; break;
                default: W = r2W; O = r2O; break;
            }
        }
        int kTiles = K >> 6;
        int k0 = (tile % kTiles) * 64, n0 = (tile / kTiles) * 64;
        int c = tid & 63, r4 = tid >> 6;
        #pragma unroll
        for (int rr = 0; rr < 64; rr += 4) {
            int r = rr + r4;
            T[r][c] = W[(size_t)(k0 + r) * 256 + n0 + c];
        }
        __syncthreads();
        #pragma unroll
        for (int rr = 0; rr < 64; rr += 4) {
            int n = rr + r4;
            O[bidx(n0 + n, k0 + c)] = f2bf(T[c][n]);
        }
    } else if (bid < 512) {
        if (tid < 8) { ss[tid] = 0.f; sq[tid] = 0.f; }
        __syncthreads();
        int gt = (bid - 256) * 256 + tid;
        float s = 0.f, q = 0.f;
        for (int e = gt; e < 32768*8; e += 256*256) { float v = contp[e]; s += v; q += v*v; }
        int f = gt & 7;
        atomicAdd(&ss[f], s);
        atomicAdd(&sq[f], q);
        __syncthreads();
        if (tid < 8) { atomicAdd(&stats[tid], ss[tid]); atomicAdd(&stats[8+tid], sq[tid]); }
    } else if (bid < 624) {
        int i = (bid - 512) * 256 + tid;
        unsigned char v = msrc[i];
        bool u8  = v && (i & 3);
        bool i32 = v && !(i & 3) && ((i & 7) == 4);
        unsigned long long bu = __ballot(u8);
        unsigned long long bi = __ballot(i32);
        if ((tid & 63) == 0) {
            if (bu) atomicOr(&flags[0], 1);
            if (bi) atomicOr(&flags[1], 1);
        }
    } else {
        #pragma unroll
        for (int j = 0; j < 4; ++j) flag[tid*4 + j] = 0;
        __syncthreads();
        if (tid < 128) flag[qidx[tid]] = 1;
        __syncthreads();
        int loc[4], cnt = 0;
        #pragma unroll
        for (int j = 0; j < 4; ++j) { loc[j] = 1 - flag[tid*4 + j]; cnt += loc[j]; }
        psc[tid] = cnt;
        __syncthreads();
        for (int off = 1; off < 256; off <<= 1) {
            int v = (tid >= off) ? psc[tid - off] : 0;
            __syncthreads();
            psc[tid] += v;
            __syncthreads();
        }
        int pos = psc[tid] - cnt;   // exclusive prefix
        #pragma unroll
        for (int j = 0; j < 4; ++j)
            if (loc[j]) kmap[pos++] = tid*4 + j;
    }
}

// ===========================================================================
// Merged node+cate GEMM+LN+leaky PLUS fused prep2 tail blocks.
// Blocks 0..1023: BM=64/BK=64 8-wave phase-fixed GEMM (r21 schedule).
// Blocks 1024..1079:   mask_conv   (56 x 512)
// Blocks 1080..1135:   expand_maps (56 x 512)
// Blocks 1136..2159:   cont path   (1024 x 512, 2 rows/iter)
// All prep work is independent of the GEMM (disjoint buffers / seq3 columns);
// it fills the idle capacity of the latency-bound GEMM blocks.
// prep scratch is OVERLAID into the 16KB A/red union -> LDS stays 80KB.
// ===========================================================================
__global__ __launch_bounds__(512, 4) void gemm_nc_k(
    const float* __restrict__ node, const int* __restrict__ cate,
    const float* __restrict__ table,
    const unsigned short* __restrict__ nWt, const unsigned short* __restrict__ cWt,
    const float* __restrict__ nb, const float* __restrict__ cb,
    const float* __restrict__ nlg, const float* __restrict__ nlb,
    const float* __restrict__ clg, const float* __restrict__ clb,
    unsigned short* __restrict__ Y,   // seq3bf, ld 768
    const unsigned char* __restrict__ msrc, const int* __restrict__ flags,
    unsigned char* __restrict__ mu8,
    const int* __restrict__ qidx, const int* __restrict__ kmap,
    int* __restrict__ qmap, int* __restrict__ krmap,
    const float* __restrict__ contp, const float* __restrict__ stats,
    const float* __restrict__ bn_g, const float* __restrict__ bn_b,
    const float* __restrict__ cW8, const float* __restrict__ cbias,
    const float* __restrict__ cg, const float* __restrict__ cbL)
{
    __shared__ union UN {
        unsigned short A[2][4096];
        struct { float S[64][4]; float Q[64][4]; } red;
        struct { float Ws[8][256]; float sscale[8], sshift[8];
                 float cr[2][8]; float red2[2][8]; } pc;
    } U;
    __shared__ unsigned short Bs[2][16384];
    const int t = threadIdx.x;
    const int gbid = blockIdx.x;

    if (gbid >= 1024) {
        // ------------------- fused prep2 tail -------------------
        const int pb = gbid - 1024;
        if (pb < 56) {
            // mask convert (28672 elems)
            int i = pb * 512 + t;
            int mode = flags[0] ? 0 : (flags[1] ? 1 : 2);
            unsigned char v;
            if (mode == 0)      v = msrc[i] ? 1 : 0;
            else if (mode == 1) v = ((const int*)msrc)[i] ? 1 : 0;
            else                v = ((const long long*)msrc)[i] ? 1 : 0;
            mu8[i] = v;
        } else if (pb < 112) {
            // expand maps
            int i = (pb - 56) * 512 + t;
            if (i < 32*128) { int b = i >> 7; int t2 = i & 127; qmap[i] = b*1024 + qidx[t2]; }
            if (i < 32*896) { int b = i / 896; int t2 = i - b*896; krmap[i] = b*1024 + kmap[t2]; }
        } else {
            // cont path: 1024 blocks x 512 threads, 2 rows per iteration
            const int cid = pb - 112;          // 0..1023
            const int half = t >> 8;           // 0/1
            const int t2 = t & 255;
            float* wsf = &U.pc.Ws[0][0];
            #pragma unroll
            for (int k = 0; k < 4; ++k) wsf[t + k*512] = cW8[t + k*512];
            if (t < 8) {
                float mean = stats[t] * (1.0f/32768.0f);
                float var  = stats[8+t] * (1.0f/32768.0f) - mean*mean;
                float r = rsqrtf(var + EPSV);
                float sc = r * bn_g[t];
                U.pc.sscale[t] = sc;
                U.pc.sshift[t] = bn_b[t] - mean*sc;
            }
            __syncthreads();
            int lane = t2 & 63, wv = t2 >> 6;
            float gv = cg[t2], bv = cbL[t2], biasv = cbias[t2];
            for (int row = cid*2 + half; row < 32768; row += 2048) {
                if (t2 < 8)
                    U.pc.cr[half][t2] = contp[(size_t)row*8 + t2]*U.pc.sscale[t2] + U.pc.sshift[t2];
                __syncthreads();
                float acc = biasv;
                #pragma unroll
                for (int d = 0; d < 8; ++d) acc += U.pc.cr[half][d]*U.pc.Ws[d][t2];
                float s = acc;
                #pragma unroll
                for (int o = 32; o; o >>= 1) s += __shfl_xor(s, o);
                if (lane == 0) U.pc.red2[half][wv] = s;
                __syncthreads();
                float mu = (U.pc.red2[half][0]+U.pc.red2[half][1]
                           +U.pc.red2[half][2]+U.pc.red2[half][3]) * (1.0f/256.0f);
                float dc = acc - mu;
                float qv = dc*dc;
                #pragma unroll
                for (int o = 32; o; o >>= 1) qv += __shfl_xor(qv, o);
                if (lane == 0) U.pc.red2[half][4+wv] = qv;
                __syncthreads();
                float var = (U.pc.red2[half][4]+U.pc.red2[half][5]
                            +U.pc.red2[half][6]+U.pc.red2[half][7]) * (1.0f/256.0f);
                float y = dc * rsqrtf(var + EPSV) * gv + bv;
                y = (y >= 0.f) ? y : 0.01f*y;
                Y[(size_t)row*768 + 512 + t2] = f2bf(y);
                __syncthreads();
            }
        }
        return;
    }

    // ------------------- GEMM blocks (r21 schedule) -------------------
    const bool isC = gbid >= 512;
    const int bm = (isC ? gbid - 512 : gbid) * 64;
    const int w = t >> 6, l = t & 63, lr = l & 15, lg = l >> 4;
    const int wm = w >> 2, wn = w & 3;
    const int ar = t >> 3;             // 0..63
    const int ac = (t & 7) * 8;        // 8 fp32 per thread per step
    const int aw = ((ac >> 5) << 11) + ((ar >> 4) << 9)
                 + (((ac >> 3) & 3) << 7) + ((ar & 15) << 3);

    const unsigned short* Bc = isC ? cWt : nWt;
    const float* bias = isC ? cb : nb;
    const float* lng  = isC ? clg : nlg;
    const float* lnbp = isC ? clb : nlb;
    const int colOff = isC ? 256 : 0;

    const float* apf = node + (size_t)(bm + ar) * 1024 + ac;
    int4 idx4 = {0,0,0,0};
    if (isC) idx4 = *(const int4*)&cate[(bm + ar) * 4];

    float4v acc[2][4];
    #pragma unroll
    for (int i = 0; i < 2; ++i)
        #pragma unroll
        for (int j = 0; j < 4; ++j) acc[i][j] = (float4v)0.f;

    float4 rA0, rA1;

    auto loadA = [&](int s) {
        const float* p;
        if (isC) {
            int kt = s * 64 + ac;
            int g = kt >> 8;
            int idx = (g == 0) ? idx4.x : (g == 1) ? idx4.y : (g == 2) ? idx4.z : idx4.w;
            p = table + (size_t)idx * 256 + (kt & 255);
        } else {
            p = apf + s * 64;
        }
        rA0 = *(const float4*)p;
        rA1 = *(const float4*)(p + 4);
    };
    auto writeA = [&](unsigned short* Ab) {
        short8v v;
        v[0] = (short)f2bf(rA0.x); v[1] = (short)f2bf(rA0.y);
        v[2] = (short)f2bf(rA0.z); v[3] = (short)f2bf(rA0.w);
        v[4] = (short)f2bf(rA1.x); v[5] = (short)f2bf(rA1.y);
        v[6] = (short)f2bf(rA1.z); v[7] = (short)f2bf(rA1.w);
        *(short8v*)&Ab[aw] = v;
    };
    auto comp = [&](const unsigned short* Ab, const unsigned short* bsb) {
        #pragma unroll
        for (int kk = 0; kk < 2; ++kk) {
            short8v af[2], bf[4];
            #pragma unroll
            for (int i = 0; i < 2; ++i)
                af[i] = *(const short8v*)&Ab[kk*2048 + ((wm*2 + i) << 9) + (lg << 7) + (lr << 3)];
            #pragma unroll
            for (int j = 0; j < 4; ++j)
                bf[j] = *(const short8v*)&bsb[kk*8192 + ((wn*4 + j) << 9) + (lg << 7) + (lr << 3)];
            #pragma unroll
            for (int i = 0; i < 2; ++i)
                #pragma unroll
                for (int j = 0; j < 4; ++j)
                    acc[i][j] = __builtin_amdgcn_mfma_f32_16x16x32_bf16(af[i], bf[j], acc[i][j], 0, 0, 0);
        }
    };

    // prologue: fill A[0] + B[0], drain, barrier
    issue_b8(Bc, 0, &Bs[0][0], w, l);
    loadA(0);
    writeA(U.A[0]);
    VMCNT_BAR(0);

    for (int s = 0; s < 16; ++s) {
        const int cur = s & 1;
        if (s + 1 < 16) {
            issue_b8(Bc, s + 1, &Bs[1 - cur][0], w, l);   // B(s+1): covered by comp
            loadA(s + 1);                                  // A(s+1): covered by comp
        }
        __builtin_amdgcn_sched_barrier(0);                 // pin loads above comp
        comp(U.A[cur], &Bs[cur][0]);
        if (s + 1 < 16) {
            writeA(U.A[1 - cur]);                          // auto-waits A(s+1) (covered)
            VMCNT_BAR(0);                                  // drains B(s+1) (covered)
        }
    }

    // ---- fused LN + leaky epilogue (per-wave 32x64 sub-tile) ----
    #pragma unroll
    for (int j = 0; j < 4; ++j) {
        float bvj = bias[wn*64 + j*16 + lr];
        #pragma unroll
        for (int i = 0; i < 2; ++i)
            #pragma unroll
            for (int r4 = 0; r4 < 4; ++r4) acc[i][j][r4] += bvj;
    }
    __syncthreads();
    #pragma unroll
    for (int i = 0; i < 2; ++i) {
        float ps[4], qs[4];
        #pragma unroll
        for (int r4 = 0; r4 < 4; ++r4) {
            float a0 = acc[i][0][r4], a1 = acc[i][1][r4],
                  a2 = acc[i][2][r4], a3 = acc[i][3][r4];
            ps[r4] = (a0 + a1) + (a2 + a3);
            qs[r4] = (a0*a0 + a1*a1) + (a2*a2 + a3*a3);
        }
        #pragma unroll
        for (int o = 1; o < 16; o <<= 1)
            #pragma unroll
            for (int r4 = 0; r4 < 4; ++r4) {
                ps[r4] += __shfl_xor(ps[r4], o);
                qs[r4] += __shfl_xor(qs[r4], o);
            }
        if (lr == 0) {
            #pragma unroll
            for (int r4 = 0; r4 < 4; ++r4) {
                int rlc = wm*32 + i*16 + lg*4 + r4;
                U.red.S[rlc][wn] = ps[r4];
                U.red.Q[rlc][wn] = qs[r4];
            }
        }
    }
    __syncthreads();
    #pragma unroll
    for (int i = 0; i < 2; ++i) {
        float mu[4], rstd[4];
        #pragma unroll
        for (int r4 = 0; r4 < 4; ++r4) {
            int rlc = wm*32 + i*16 + lg*4 + r4;
            float s  = (U.red.S[rlc][0] + U.red.S[rlc][1]) + (U.red.S[rlc][2] + U.red.S[rlc][3]);
            float qq = (U.red.Q[rlc][0] + U.red.Q[rlc][1]) + (U.red.Q[rlc][2] + U.red.Q[rlc][3]);
            float m_ = s * (1.0f/256.0f);
            mu[r4] = m_;
            rstd[r4] = rsqrtf(qq * (1.0f/256.0f) - m_*m_ + EPSV);
        }
        #pragma unroll
        for (int j = 0; j < 4; ++j) {
            int c = wn*64 + j*16 + lr;
            float gv = lng[c], b2 = lnbp[c];
            #pragma unroll
            for (int r4 = 0; r4 < 4; ++r4) {
                int row = bm + wm*32 + i*16 + lg*4 + r4;
                float y = (acc[i][j][r4] - mu[r4]) * rstd[r4] * gv + b2;
                y = (y >= 0.f) ? y : 0.01f*y;
                Y[(size_t)row * 768 + colOff + c] = f2bf(y);
            }
        }
    }
}

// ===========================================================================
// comb GEMM+LN+pos: 8-wave template, phase-fixed schedule. BM=64, BK=64,
// 512 blocks x 512 threads, 12 steps, A bf16 [32768][768].
// ===========================================================================
__global__ __launch_bounds__(512, 4) void gemm_comb_k(
    const unsigned short* __restrict__ A,
    const unsigned short* __restrict__ Bc,
    const float* __restrict__ bias,
    const float* __restrict__ lng, const float* __restrict__ lnbp,
    const float* __restrict__ pos,
    unsigned short* __restrict__ Y)          // seqbf [32768][256]
{
    __shared__ union UC {
        unsigned short A[2][4096];
        struct { float S[64][4]; float Q[64][4]; } red;
    } U;
    __shared__ unsigned short Bs[2][16384];
    const int t = threadIdx.x;
    const int bm = blockIdx.x * 64;
    const int w = t >> 6, l = t & 63, lr = l & 15, lg = l >> 4;
    const int wm = w >> 2, wn = w & 3;
    const int ar = t >> 3;
    const int ak = (t & 7) * 8;
    const int aw = ((ak >> 5) << 11) + ((ar >> 4) << 9)
                 + (((ak >> 3) & 3) << 7) + ((ar & 15) << 3);

    const unsigned short* ap = A + (size_t)(bm + ar) * 768 + ak;

    float4v acc[2][4];
    #pragma unroll
    for (int i = 0; i < 2; ++i)
        #pragma unroll
        for (int j = 0; j < 4; ++j) acc[i][j] = (float4v)0.f;

    short8v aA;

    auto comp = [&](const unsigned short* Ab, const unsigned short* bsb) {
        #pragma unroll
        for (int kk = 0; kk < 2; ++kk) {
            short8v af[2], bf[4];
            #pragma unroll
            for (int i = 0; i < 2; ++i)
                af[i] = *(const short8v*)&Ab[kk*2048 + ((wm*2 + i) << 9) + (lg << 7) + (lr << 3)];
            #pragma unroll
            for (int j = 0; j < 4; ++j)
                bf[j] = *(const short8v*)&bsb[kk*8192 + ((wn*4 + j) << 9) + (lg << 7) + (lr << 3)];
            #pragma unroll
            for (int i = 0; i < 2; ++i)
                #pragma unroll
                for (int j = 0; j < 4; ++j)
                    acc[i][j] = __builtin_amdgcn_mfma_f32_16x16x32_bf16(af[i], bf[j], acc[i][j], 0, 0, 0);
        }
    };

    issue_b8(Bc, 0, &Bs[0][0], w, l);
    aA = *(const short8v*)(ap);
    *(short8v*)&U.A[0][aw] = aA;
    VMCNT_BAR(0);

    for (int s = 0; s < 12; ++s) {
        const int cur = s & 1;
        if (s + 1 < 12) {
            issue_b8(Bc, s + 1, &Bs[1 - cur][0], w, l);
            aA = *(const short8v*)(ap + (s + 1) * 64);
        }
        __builtin_amdgcn_sched_barrier(0);
        comp(U.A[cur], &Bs[cur][0]);
        if (s + 1 < 12) {
            *(short8v*)&U.A[1 - cur][aw] = aA;
            VMCNT_BAR(0);
        }
    }

    // ---- fused LN + pos epilogue (per-wave 32x64 sub-tile) ----
    #pragma unroll
    for (int j = 0; j < 4; ++j) {
        float bvj = bias[wn*64 + j*16 + lr];
        #pragma unroll
        for (int i = 0; i < 2; ++i)
            #pragma unroll
            for (int r4 = 0; r4 < 4; ++r4) acc[i][j][r4] += bvj;
    }
    __syncthreads();
    #pragma unroll
    for (int i = 0; i < 2; ++i) {
        float ps[4], qs[4];
        #pragma unroll
        for (int r4 = 0; r4 < 4; ++r4) {
            float a0 = acc[i][0][r4], a1 = acc[i][1][r4],
                  a2 = acc[i][2][r4], a3 = acc[i][3][r4];
            ps[r4] = (a0 + a1) + (a2 + a3);
            qs[r4] = (a0*a0 + a1*a1) + (a2*a2 + a3*a3);
        }
        #pragma unroll
        for (int o = 1; o < 16; o <<= 1)
            #pragma unroll
            for (int r4 = 0; r4 < 4; ++r4) {
                ps[r4] += __shfl_xor(ps[r4], o);
                qs[r4] += __shfl_xor(qs[r4], o);
            }
        if (lr == 0) {
            #pragma unroll
            for (int r4 = 0; r4 < 4; ++r4) {
                int rlc = wm*32 + i*16 + lg*4 + r4;
                U.red.S[rlc][wn] = ps[r4];
                U.red.Q[rlc][wn] = qs[r4];
            }
        }
    }
    __syncthreads();
    #pragma unroll
    for (int i = 0; i < 2; ++i) {
        float mu[4], rstd[4];
        #pragma unroll
        for (int r4 = 0; r4 < 4; ++r4) {
            int rlc = wm*32 + i*16 + lg*4 + r4;
            float s  = (U.red.S[rlc][0] + U.red.S[rlc][1]) + (U.red.S[rlc][2] + U.red.S[rlc][3]);
            float qq = (U.red.Q[rlc][0] + U.red.Q[rlc][1]) + (U.red.Q[rlc][2] + U.red.Q[rlc][3]);
            float m_ = s * (1.0f/256.0f);
            mu[r4] = m_;
            rstd[r4] = rsqrtf(qq * (1.0f/256.0f) - m_*m_ + EPSV);
        }
        #pragma unroll
        for (int j = 0; j < 4; ++j) {
            int c = wn*64 + j*16 + lr;
            float gv = lng[c], b2 = lnbp[c];
            #pragma unroll
            for (int r4 = 0; r4 < 4; ++r4) {
                int row = bm + wm*32 + i*16 + lg*4 + r4;
                float y = (acc[i][j][r4] - mu[r4]) * rstd[r4] * gv + b2
                        + pos[(size_t)(row & 1023) * 256 + c];
                Y[(size_t)row * 256 + c] = f2bf(y);
            }
        }
    }
}

// ===========================================================================
// Merged Q/K/V projections, BM=64, BK=64: 960 blocks x 512 threads, 8 waves.
// Phase-fixed schedule.
// ===========================================================================
__global__ __launch_bounds__(512, 4) void gemm_qkv_k(
    const unsigned short* __restrict__ seq,
    const int* __restrict__ qmap, const int* __restrict__ krmap,
    const unsigned short* __restrict__ qWt, const unsigned short* __restrict__ kWt,
    const unsigned short* __restrict__ vWt,
    const float* __restrict__ qb, const float* __restrict__ kb, const float* __restrict__ vb,
    unsigned short* __restrict__ Qo, unsigned short* __restrict__ Ko,
    unsigned short* __restrict__ Vt)
{
    __shared__ unsigned short Asl[2][4096];
    __shared__ unsigned short Bs[2][16384];
    const int t = threadIdx.x;
    const int bid = blockIdx.x;
    int seg, bm;
    const int* gmap; const unsigned short* Bc; const float* bias;
    if (bid < 64)       { seg = 0; bm = bid * 64;         gmap = qmap;  Bc = qWt; bias = qb; }
    else if (bid < 512) { seg = 1; bm = (bid - 64) * 64;  gmap = krmap; Bc = kWt; bias = kb; }
    else                { seg = 2; bm = (bid - 512) * 64; gmap = krmap; Bc = vWt; bias = vb; }
    const int w = t >> 6, l = t & 63, lr = l & 15, lg = l >> 4;
    const int wm = w >> 2, wn = w & 3;
    const int ar = t >> 3;
    const int ak = (t & 7) * 8;
    const int aw = ((ak >> 5) << 11) + ((ar >> 4) << 9)
                 + (((ak >> 3) & 3) << 7) + ((ar & 15) << 3);

    const unsigned short* ap = seq + (size_t)gmap[bm + ar] * 256 + ak;

    float4v acc[2][4];
    #pragma unroll
    for (int i = 0; i < 2; ++i)
        #pragma unroll
        for (int j = 0; j < 4; ++j) acc[i][j] = (float4v)0.f;

    short8v aA;

    auto comp = [&](const unsigned short* Ab, const unsigned short* bsb) {
        #pragma unroll
        for (int kk = 0; kk < 2; ++kk) {
            short8v af[2], bf[4];
            #pragma unroll
            for (int i = 0; i < 2; ++i)
                af[i] = *(const short8v*)&Ab[kk*2048 + ((wm*2 + i) << 9) + (lg << 7) + (lr << 3)];
            #pragma unroll
            for (int j = 0; j < 4; ++j)
                bf[j] = *(const short8v*)&bsb[kk*8192 + ((wn*4 + j) << 9) + (lg << 7) + (lr << 3)];
            #pragma unroll
            for (int i = 0; i < 2; ++i)
                #pragma unroll
                for (int j = 0; j < 4; ++j)
                    acc[i][j] = __builtin_amdgcn_mfma_f32_16x16x32_bf16(af[i], bf[j], acc[i][j], 0, 0, 0);
        }
    };

    issue_b8(Bc, 0, &Bs[0][0], w, l);
    aA = *(const short8v*)(ap);
    *(short8v*)&Asl[0][aw] = aA;
    VMCNT_BAR(0);

    for (int s = 0; s < 4; ++s) {
        const int cur = s & 1;
        if (s + 1 < 4) {
            issue_b8(Bc, s + 1, &Bs[1 - cur][0], w, l);
            aA = *(const short8v*)(ap + (s + 1) * 64);
        }
        __builtin_amdgcn_sched_barrier(0);
        comp(Asl[cur], &Bs[cur][0]);
        if (s + 1 < 4) {
            *(short8v*)&Asl[1 - cur][aw] = aA;
            VMCNT_BAR(0);
        }
    }

    unsigned short* outp = (seg == 0) ? Qo : (seg == 1) ? Ko : Vt;
    #pragma unroll
    for (int j = 0; j < 4; ++j) {
        int c = wn*64 + j*16 + lr;
        float bvj = bias[c];
        #pragma unroll
        for (int i = 0; i < 2; ++i) {
            #pragma unroll
            for (int r4 = 0; r4 < 4; ++r4) {
                int rl = wm*32 + i*16 + lg*4 + r4;
                float val = acc[i][j][r4] + bvj;
                if (seg < 2) {
                    outp[(size_t)(bm + rl) * 256 + c] = f2bf(val);
                } else {
                    int vbk = bm / 896;
                    int kl = bm - vbk * 896 + rl;
                    outp[((size_t)vbk * 256 + c) * 896 + kl] = f2bf(val);
                }
            }
        }
    }
}

// ---------------------------------------------------------------------------
// Regression-head GEMM (BM=64, BK=64, K=256, 256 thr). EPI: 0 f32; 3 LN+leaky.
// ---------------------------------------------------------------------------
template<int EPI>
__global__ __launch_bounds__(256) void gemm_reg_k(
    const unsigned short* __restrict__ Asrc,
    const unsigned short* __restrict__ Bc,
    const float* __restrict__ bias,
    const float* __restrict__ ln_g,
    const float* __restrict__ ln_b,
    void* __restrict__ Cout)
{
    __shared__ union UR {
        unsigned short A[2][4096];
        struct { float S[64][4]; float Q[64][4]; } red;
    } U;
    __shared__ unsigned short Bs[2][16384];
    const int t = threadIdx.x;
    const int bm = blockIdx.x * 64;
    const int w = t >> 6, l = t & 63, lr = l & 15, lg = l >> 4;
    const int ar = t >> 2;
    const int ac = (t & 3) * 16;
    const int aw0 = (((t & 3) >> 1) << 11) + ((ar >> 4) << 9)
                  + ((((t & 3) * 2) & 3) << 7) + ((ar & 15) << 3);
    const int aw1 = aw0 + 128;

    const unsigned short* ap = Asrc + (size_t)(bm + ar) * 256 + ac;

    float4v acc[4][4];
    #pragma unroll
    for (int i = 0; i < 4; ++i)
        #pragma unroll
        for (int j = 0; j < 4; ++j) acc[i][j] = (float4v)0.f;

    short8v a0A, a1A, a0B, a1B;

    auto comp = [&](const unsigned short* Ab, const unsigned short* bsb) {
        #pragma unroll
        for (int kk = 0; kk < 2; ++kk) {
            short8v af[4], bf[4];
            #pragma unroll
            for (int i = 0; i < 4; ++i)
                af[i] = *(const short8v*)&Ab[kk*2048 + i*512 + lg*128 + lr*8];
            #pragma unroll
            for (int j = 0; j < 4; ++j)
                bf[j] = *(const short8v*)&bsb[kk*8192 + ((w*4 + j) << 9) + (lg << 7) + (lr << 3)];
            #pragma unroll
            for (int i = 0; i < 4; ++i)
                #pragma unroll
                for (int j = 0; j < 4; ++j)
                    acc[i][j] = __builtin_amdgcn_mfma_f32_16x16x32_bf16(af[i], bf[j], acc[i][j], 0, 0, 0);
        }
    };

    issue_b(Bc, 0, &Bs[0][0], w, l);
    issue_b(Bc, 1, &Bs[0][8192], w, l);
    a0A = *(const short8v*)(ap);
    a1A = *(const short8v*)(ap + 8);
    for (int s = 0; s < 4; ++s) {
        int cur = s & 1;
        __syncthreads();
        *(short8v*)&U.A[cur][aw0] = a0A;
        *(short8v*)&U.A[cur][aw1] = a1A;
        __syncthreads();
        if (s + 1 < 4) {
            issue_b(Bc, 2*(s+1),     &Bs[1 - cur][0],    w, l);
            issue_b(Bc, 2*(s+1) + 1, &Bs[1 - cur][8192], w, l);
            a0B = *(const short8v*)(ap + (s + 1) * 64);
            a1B = *(const short8v*)(ap + (s + 1) * 64 + 8);
        }
        comp(U.A[cur], &Bs[cur][0]);
        a0A = a0B; a1A = a1B;
    }

    #pragma unroll
    for (int j = 0; j < 4; ++j) {
        float bvj = bias[w*64 + j*16 + lr];
        #pragma unroll
        for (int i = 0; i < 4; ++i)
            #pragma unroll
            for (int r4 = 0; r4 < 4; ++r4) acc[i][j][r4] += bvj;
    }

    if (EPI == 0) {
        #pragma unroll
        for (int i = 0; i < 4; ++i)
            #pragma unroll
            for (int j = 0; j < 4; ++j) {
                int c = w*64 + j*16 + lr;
                #pragma unroll
                for (int r4 = 0; r4 < 4; ++r4) {
                    int rl = i*16 + lg*4 + r4;
                    ((float*)Cout)[(size_t)(bm + rl) * 256 + c] = acc[i][j][r4];
                }
            }
    } else {
        __syncthreads();
        #pragma unroll
        for (int i = 0; i < 4; ++i) {
            float ps[4], qs[4];
            #pragma unroll
            for (int r4 = 0; r4 < 4; ++r4) {
                float a0 = acc[i][0][r4], a1 = acc[i][1][r4],
                      a2 = acc[i][2][r4], a3 = acc[i][3][r4];
                ps[r4] = (a0 + a1) + (a2 + a3);
                qs[r4] = (a0*a0 + a1*a1) + (a2*a2 + a3*a3);
            }
            #pragma unroll
            for (int o = 1; o < 16; o <<= 1)
                #pragma unroll
                for (int r4 = 0; r4 < 4; ++r4) {
                    ps[r4] += __shfl_xor(ps[r4], o);
                    qs[r4] += __shfl_xor(qs[r4], o);
                }
            if (lr == 0) {
                #pragma unroll
                for (int r4 = 0; r4 < 4; ++r4) {
                    U.red.S[i*16 + lg*4 + r4][w] = ps[r4];
                    U.red.Q[i*16 + lg*4 + r4][w] = qs[r4];
                }
            }
        }
        __syncthreads();
        #pragma unroll
        for (int i = 0; i < 4; ++i) {
            float mu[4], rstd[4];
            #pragma unroll
            for (int r4 = 0; r4 < 4; ++r4) {
                int rl = i*16 + lg*4 + r4;
                float s  = (U.red.S[rl][0] + U.red.S[rl][1]) + (U.red.S[rl][2] + U.red.S[rl][3]);
                float qq = (U.red.Q[rl][0] + U.red.Q[rl][1]) + (U.red.Q[rl][2] + U.red.Q[rl][3]);
                float m_ = s * (1.0f/256.0f);
                mu[r4] = m_;
                rstd[r4] = rsqrtf(qq * (1.0f/256.0f) - m_*m_ + EPSV);
            }
            #pragma unroll
            for (int j = 0; j < 4; ++j) {
                int c = w*64 + j*16 + lr;
                float gv = ln_g[c], b2 = ln_b[c];
                #pragma unroll
                for (int r4 = 0; r4 < 4; ++r4) {
                    int row = bm + i*16 + lg*4 + r4;
                    float y = (acc[i][j][r4] - mu[r4]) * rstd[r4] * gv + b2;
                    y = (y >= 0.f) ? y : 0.01f*y;
                    ((unsigned short*)Cout)[(size_t)row * 256 + c] = f2bf(y);
                }
            }
        }
    }
}

// ---------------------------------------------------------------------------
// MFMA flash attention. Grid 512 = (b, h, qhalf). 4 waves/block.
// ---------------------------------------------------------------------------
__global__ __launch_bounds__(256) void attn_mfma_k(
    const unsigned short* __restrict__ Qb,
    const unsigned short* __restrict__ Kb,
    const unsigned short* __restrict__ Vtb,
    const unsigned char* __restrict__ mask,
    unsigned short* __restrict__ out)
{
    __shared__ unsigned short Pw[4][16][72];
    const int t = threadIdx.x;
    const int w = t >> 6, l = t & 63;
    const int lr = l & 15, lg = l >> 4;
    const int bx = blockIdx.x;
    const int qh = bx & 1, h = (bx >> 1) & 7, b = bx >> 4;
    const int qrow0 = b*128 + qh*64 + w*16;

    short8v qf = *(const short8v*)&Qb[(size_t)(qrow0 + lr)*256 + h*32 + lg*8];

    const unsigned short* Kbase = Kb + (size_t)b*896*256 + h*32;
    const unsigned short* Vbase = Vtb + ((size_t)b*256 + h*32)*896;
    const unsigned char* mrow = mask + b*896;

    float4v O0 = (float4v)0.f, O1 = (float4v)0.f;
    float m[4], lsum[4];
    #pragma unroll
    for (int r = 0; r < 4; ++r) { m[r] = -3.0e38f; lsum[r] = 0.f; }

    short8v kf[4], vf[4];
    int mk[4];
    #pragma unroll
    for (int i = 0; i < 4; ++i) {
        kf[i] = *(const short8v*)&Kbase[(size_t)(i*16 + lr)*256 + lg*8];
        mk[i] = mrow[i*16 + lr];
    }
    #pragma unroll
    for (int kc = 0; kc < 2; ++kc)
        #pragma unroll
        for (int nt = 0; nt < 2; ++nt)
            vf[kc*2+nt] = *(const short8v*)&Vbase[(size_t)(nt*16 + lr)*896 + kc*32 + lg*8];

    for (int kt3 = 0; kt3 < 14; ++kt3) {
        const int kb2 = kt3*64 + 64;
        short8v kf2[4], vf2[4];
        int mk2[4];
        if (kt3 < 13) {
            #pragma unroll
            for (int i = 0; i < 4; ++i) {
                kf2[i] = *(const short8v*)&Kbase[(size_t)(kb2 + i*16 + lr)*256 + lg*8];
                mk2[i] = mrow[kb2 + i*16 + lr];
            }
            #pragma unroll
            for (int kc = 0; kc < 2; ++kc)
                #pragma unroll
                for (int nt = 0; nt < 2; ++nt)
                    vf2[kc*2+nt] = *(const short8v*)&Vbase[(size_t)(nt*16 + lr)*896 + kb2 + kc*32 + lg*8];
        }
        float4v s4[4];
        #pragma unroll
        for (int i = 0; i < 4; ++i)
            s4[i] = __builtin_amdgcn_mfma_f32_16x16x32_bf16(qf, kf[i], (float4v)0.f, 0, 0, 0);
        #pragma unroll
        for (int i = 0; i < 4; ++i)
            #pragma unroll
            for (int r = 0; r < 4; ++r)
                s4[i][r] = mk[i] ? -1e9f : s4[i][r] * 0.17677669529663687f;
        float tm[4];
        #pragma unroll
        for (int r = 0; r < 4; ++r)
            tm[r] = fmaxf(fmaxf(s4[0][r], s4[1][r]), fmaxf(s4[2][r], s4[3][r]));
        #pragma unroll
        for (int o = 1; o < 16; o <<= 1)
            #pragma unroll
            for (int r = 0; r < 4; ++r) tm[r] = fmaxf(tm[r], __shfl_xor(tm[r], o));
        float resc[4];
        #pragma unroll
        for (int r = 0; r < 4; ++r) {
            float mn = fmaxf(m[r], tm[r]);
            resc[r] = __expf(m[r] - mn);
            m[r] = mn;
        }
        float rs[4] = {0.f, 0.f, 0.f, 0.f};
        #pragma unroll
        for (int i = 0; i < 4; ++i)
            #pragma unroll
            for (int r = 0; r < 4; ++r) {
                float p = __expf(s4[i][r] - m[r]);
                s4[i][r] = p;
                rs[r] += p;
            }
        #pragma unroll
        for (int o = 1; o < 16; o <<= 1)
            #pragma unroll
            for (int r = 0; r < 4; ++r) rs[r] += __shfl_xor(rs[r], o);
        #pragma unroll
        for (int r = 0; r < 4; ++r) lsum[r] = lsum[r]*resc[r] + rs[r];
        #pragma unroll
        for (int r = 0; r < 4; ++r) { O0[r] *= resc[r]; O1[r] *= resc[r]; }
        #pragma unroll
        for (int i = 0; i < 4; ++i)
            #pragma unroll
            for (int r = 0; r < 4; ++r)
                Pw[w][lg*4 + r][i*16 + lr] = f2bf(s4[i][r]);
        #pragma unroll
        for (int kc = 0; kc < 2; ++kc) {
            short8v pf = *(const short8v*)&Pw[w][lr][kc*32 + lg*8];
            O0 = __builtin_amdgcn_mfma_f32_16x16x32_bf16(pf, vf[kc*2+0], O0, 0, 0, 0);
            O1 = __builtin_amdgcn_mfma_f32_16x16x32_bf16(pf, vf[kc*2+1], O1, 0, 0, 0);
        }
        if (kt3 < 13) {
            #pragma unroll
            for (int i = 0; i < 4; ++i) { kf[i] = kf2[i]; mk[i] = mk2[i]; vf[i] = vf2[i]; }
        }
    }
    #pragma unroll
    for (int r = 0; r < 4; ++r) {
        float inv = 1.0f / lsum[r];
        size_t row = (size_t)(qrow0 + lg*4 + r);
        out[row*256 + h*32 + lr]      = f2bf(O0[r] * inv);
        out[row*256 + h*32 + 16 + lr] = f2bf(O1[r] * inv);
    }
}

// ---------------------------------------------------------------------------
extern "C" void kernel_launch(void* const* d_in, const int* in_sizes, int n_in,
                              void* d_out, int out_size, void* d_ws, size_t ws_size,
                              hipStream_t stream)
{
    const float* node       = (const float*)d_in[0];
    const int*   cate       = (const int*)d_in[1];
    const float* cont       = (const float*)d_in[2];
    const int*   qidx       = (const int*)d_in[3];
    const unsigned char* mask = (const unsigned char*)d_in[4];
    const float* cate_table = (const float*)d_in[5];
    const float* pos_emb    = (const float*)d_in[6];
    const float* node_W     = (const float*)d_in[7];
    const float* node_b     = (const float*)d_in[8];
    const float* node_ln_g  = (const float*)d_in[9];
    const float* node_ln_b  = (const float*)d_in[10];
    const float* cate_W     = (const float*)d_in[11];
    const float* cate_b     = (const float*)d_in[12];
    const float* cate_ln_g  = (const float*)d_in[13];
    const float* cate_ln_b  = (const float*)d_in[14];
    const float* bn_g       = (const float*)d_in[15];
    const float* bn_b       = (const float*)d_in[16];
    const float* cont_W     = (const float*)d_in[17];
    const float* cont_b     = (const float*)d_in[18];
    const float* cont_ln_g  = (const float*)d_in[19];
    const float* cont_ln_b  = (const float*)d_in[20];
    const float* comb_W     = (const float*)d_in[21];
    const float* comb_b     = (const float*)d_in[22];
    const float* comb_ln_g  = (const float*)d_in[23];
    const float* comb_ln_b  = (const float*)d_in[24];
    const float* q_W        = (const float*)d_in[25];
    const float* q_b        = (const float*)d_in[26];
    const float* k_W        = (const float*)d_in[27];
    const float* k_b        = (const float*)d_in[28];
    const float* v_W        = (const float*)d_in[29];
    const float* v_b        = (const float*)d_in[30];
    const float* reg_W1     = (const float*)d_in[31];
    const float* reg_b1     = (const float*)d_in[32];
    const float* reg_ln_g   = (const float*)d_in[33];
    const float* reg_ln_b   = (const float*)d_in[34];
    const float* reg_W2     = (const float*)d_in[35];
    const float* reg_b2     = (const float*)d_in[36];

    char* ws = (char*)d_ws;
    unsigned short* seq3bf = (unsigned short*)(ws + 0);          // 32768*768*2
    unsigned short* seqbf  = (unsigned short*)(ws + 83886080);   // 32768*256*2
    unsigned short* Qbf    = (unsigned short*)(ws + 100663296);
    unsigned short* Kbf    = (unsigned short*)(ws + 102760448);
    unsigned short* Vtbf   = (unsigned short*)(ws + 117440512);
    unsigned short* AObf   = (unsigned short*)(ws + 132120576);
    unsigned short* Hbf    = (unsigned short*)(ws + 0);          // reuse seq3bf region
    float* stats = (float*)(ws + 165675008);
    int*   flags = (int*)  (ws + 165675072);
    int*   kmap  = (int*)  (ws + 165675136);
    int*   qmap  = (int*)  (ws + 165678720);
    int*   krmap = (int*)  (ws + 165695104);
    unsigned char* mu8 = (unsigned char*)(ws + 165809792);
    unsigned short* node_Wt = (unsigned short*)(ws + 165838464);
    unsigned short* cate_Wt = (unsigned short*)(ws + 166362752);
    unsigned short* comb_Wt = (unsigned short*)(ws + 166887040);
    unsigned short* q_Wt    = (unsigned short*)(ws + 167280256);
    unsigned short* k_Wt    = (unsigned short*)(ws + 167411328);
    unsigned short* v_Wt    = (unsigned short*)(ws + 167542400);
    unsigned short* r1_Wt   = (unsigned short*)(ws + 167673472);
    unsigned short* r2_Wt   = (unsigned short*)(ws + 167804544);
    float* outp = (float*)d_out;

    hipMemsetAsync(stats, 0, 128, stream);
    // prep1: wt_all + bn_stats + mask_sniff + build_maps (625 blocks)
    prep1_k<<<625, 256, 0, stream>>>(cont, stats, mask, flags, qidx, kmap,
        node_W, cate_W, comb_W, q_W, k_W, v_W, reg_W1, reg_W2,
        node_Wt, cate_Wt, comb_Wt, q_Wt, k_Wt, v_Wt, r1_Wt, r2_Wt);
    // node+cate GEMM with fused prep2 tail (1024 GEMM + 1136 prep blocks)
    gemm_nc_k<<<2160, 512, 0, stream>>>(node, cate, cate_table, node_Wt, cate_Wt,
        node_b, cate_b, node_ln_g, node_ln_b, cate_ln_g, cate_ln_b, seq3bf,
        mask, flags, mu8, qidx, kmap, qmap, krmap,
        cont, stats, bn_g, bn_b, cont_W, cont_b, cont_ln_g, cont_ln_b);
    // comb (8-wave, phase-fixed: 512 x 512)
    gemm_comb_k<<<512, 512, 0, stream>>>(seq3bf, comb_Wt, comb_b,
        comb_ln_g, comb_ln_b, pos_emb, seqbf);
    // Q/K/V merged (8-wave, phase-fixed: 960 x 512)
    gemm_qkv_k<<<960, 512, 0, stream>>>(seqbf, qmap, krmap, q_Wt, k_Wt, v_Wt,
        q_b, k_b, v_b, Qbf, Kbf, Vtbf);
    // attention
    attn_mfma_k<<<512, 256, 0, stream>>>(Qbf, Kbf, Vtbf, mu8, AObf);
    // regression head
    gemm_reg_k<3><<<64, 256, 0, stream>>>(AObf, r1_Wt, reg_b1, reg_ln_g, reg_ln_b, Hbf);
    gemm_reg_k<0><<<64, 256, 0, stream>>>(Hbf, r2_Wt, reg_b2, nullptr, nullptr, outp);
}

// Round 26
// 234.897 us; speedup vs baseline: 1.0301x; 1.0301x over previous
//
#include <hip/hip_runtime.h>
#include <cstdint>

#define EPSV 1e-5f
#define AS1 __attribute__((address_space(1)))
#define AS3 __attribute__((address_space(3)))

#define VMCNT_BAR(N) do { \
    asm volatile("s_waitcnt vmcnt(" #N ") lgkmcnt(0)" ::: "memory"); \
    __builtin_amdgcn_sched_barrier(0); \
    __builtin_amdgcn_s_barrier(); } while (0)

typedef __attribute__((ext_vector_type(8))) short short8v;   // 8 bf16
typedef __attribute__((ext_vector_type(4))) float float4v;

__device__ inline unsigned short f2bf(float f) {
    union { float f; unsigned int u; } v; v.f = f;
    unsigned int r = v.u + 0x7FFF + ((v.u >> 16) & 1);
    return (unsigned short)(r >> 16);
}

// Chunked B layout: per 32-wide K-step a 16KB chunk in MFMA-fragment order.
__device__ inline size_t bidx(int n, int k) {
    return ((size_t)(k >> 5) << 13) + ((size_t)(n >> 4) << 9)
         + (((k >> 3) & 3) << 7) + ((n & 15) << 3) + (k & 7);
}

__device__ inline void gld16(const unsigned short* g, unsigned short* d) {
    __builtin_amdgcn_global_load_lds((const AS1 void*)g, (AS3 void*)d, 16, 0, 0);
}

// 256-thread form: one wave fills its share of chunk s (8192 elems)
__device__ inline void issue_b(const unsigned short* Bc, int s, unsigned short* bsb,
                               int w, int l) {
    const unsigned short* g = Bc + ((size_t)s << 13) + (w << 9) + (l << 3);
    unsigned short* d = bsb + (w << 9) + (l << 3);
    #pragma unroll
    for (int i = 0; i < 4; ++i)
        gld16(g + (i << 11), d + (i << 11));
}

// 512-thread form: 8 waves fill chunk-pair (2s, 2s+1) = 32KB into bsb[16384]
__device__ inline void issue_b8(const unsigned short* Bc, int s, unsigned short* bsb,
                                int w, int l) {
    const unsigned short* g = Bc + ((size_t)(2 * s) << 13);
    #pragma unroll
    for (int i = 0; i < 4; ++i) {
        int blk = (w + i * 8) << 9;
        gld16(g + blk + (l << 3), bsb + blk + (l << 3));
    }
}

// ===========================================================================
// prep1: wt_all (bid 0..255) + bn_stats (256..511) + mask_sniff (512..623)
//        + build_maps (624, 256-thread scan). Uniform per-block branch.
// ===========================================================================
__global__ __launch_bounds__(256) void prep1_k(
    const float* __restrict__ contp, float* __restrict__ stats,
    const unsigned char* __restrict__ msrc, int* __restrict__ flags,
    const int* __restrict__ qidx, int* __restrict__ kmap,
    const float* __restrict__ nW, const float* __restrict__ cW, const float* __restrict__ mW,
    const float* __restrict__ qW, const float* __restrict__ kW, const float* __restrict__ vW,
    const float* __restrict__ r1W, const float* __restrict__ r2W,
    unsigned short* __restrict__ nO, unsigned short* __restrict__ cO, unsigned short* __restrict__ mO,
    unsigned short* __restrict__ qO, unsigned short* __restrict__ kO, unsigned short* __restrict__ vO,
    unsigned short* __restrict__ r1O, unsigned short* __restrict__ r2O)
{
    __shared__ float T[64][65];
    __shared__ float ss[8], sq[8];
    __shared__ int flag[1024];
    __shared__ int psc[256];
    const int bid = blockIdx.x;
    const int tid = threadIdx.x;

    if (bid < 256) {
        const float* W; unsigned short* O; int K, tile;
        if (bid < 64)       { W = nW; O = nO; K = 1024; tile = bid; }
        else if (bid < 128) { W = cW; O = cO; K = 1024; tile = bid - 64; }
        else if (bid < 176) { W = mW; O = mO; K = 768;  tile = bid - 128; }
        else {
            int s = (bid - 176) >> 4; tile = (bid - 176) & 15; K = 256;
            switch (s) {
                case 0: W = qW;  O = qO;  break;
                case 1: W = kW;  O = kO;  break;
                case 2: W = vW;  O = vO;  break;
                case 3: W = r1W; O = r1O; break;
                default: W = r2W; O = r2O; break;
            }
        }
        int kTiles = K >> 6;
        int k0 = (tile % kTiles) * 64, n0 = (tile / kTiles) * 64;
        int c = tid & 63, r4 = tid >> 6;
        #pragma unroll
        for (int rr = 0; rr < 64; rr += 4) {
            int r = rr + r4;
            T[r][c] = W[(size_t)(k0 + r) * 256 + n0 + c];
        }
        __syncthreads();
        #pragma unroll
        for (int rr = 0; rr < 64; rr += 4) {
            int n = rr + r4;
            O[bidx(n0 + n, k0 + c)] = f2bf(T[c][n]);
        }
    } else if (bid < 512) {
        if (tid < 8) { ss[tid] = 0.f; sq[tid] = 0.f; }
        __syncthreads();
        int gt = (bid - 256) * 256 + tid;
        float s = 0.f, q = 0.f;
        for (int e = gt; e < 32768*8; e += 256*256) { float v = contp[e]; s += v; q += v*v; }
        int f = gt & 7;
        atomicAdd(&ss[f], s);
        atomicAdd(&sq[f], q);
        __syncthreads();
        if (tid < 8) { atomicAdd(&stats[tid], ss[tid]); atomicAdd(&stats[8+tid], sq[tid]); }
    } else if (bid < 624) {
        int i = (bid - 512) * 256 + tid;
        unsigned char v = msrc[i];
        bool u8  = v && (i & 3);
        bool i32 = v && !(i & 3) && ((i & 7) == 4);
        unsigned long long bu = __ballot(u8);
        unsigned long long bi = __ballot(i32);
        if ((tid & 63) == 0) {
            if (bu) atomicOr(&flags[0], 1);
            if (bi) atomicOr(&flags[1], 1);
        }
    } else {
        #pragma unroll
        for (int j = 0; j < 4; ++j) flag[tid*4 + j] = 0;
        __syncthreads();
        if (tid < 128) flag[qidx[tid]] = 1;
        __syncthreads();
        int loc[4], cnt = 0;
        #pragma unroll
        for (int j = 0; j < 4; ++j) { loc[j] = 1 - flag[tid*4 + j]; cnt += loc[j]; }
        psc[tid] = cnt;
        __syncthreads();
        for (int off = 1; off < 256; off <<= 1) {
            int v = (tid >= off) ? psc[tid - off] : 0;
            __syncthreads();
            psc[tid] += v;
            __syncthreads();
        }
        int pos = psc[tid] - cnt;   // exclusive prefix
        #pragma unroll
        for (int j = 0; j < 4; ++j)
            if (loc[j]) kmap[pos++] = tid*4 + j;
    }
}

// ===========================================================================
// prep2: mask_conv (bid 0..111) + expand_maps (112..223) + cont path (224..2271)
// ===========================================================================
__global__ __launch_bounds__(256) void prep2_k(
    const unsigned char* __restrict__ msrc, const int* __restrict__ flags,
    unsigned char* __restrict__ mu8,
    const int* __restrict__ qidx, const int* __restrict__ kmap,
    int* __restrict__ qmap, int* __restrict__ krmap,
    const float* __restrict__ contp, const float* __restrict__ stats,
    const float* __restrict__ bn_g, const float* __restrict__ bn_b,
    const float* __restrict__ W, const float* __restrict__ bias,
    const float* __restrict__ g, const float* __restrict__ bL,
    unsigned short* __restrict__ seq3)
{
    __shared__ float Ws[8][256];
    __shared__ float sscale[8], sshift[8];
    __shared__ float cr[8];
    __shared__ float red[8];
    const int bid = blockIdx.x, tid = threadIdx.x;

    if (bid < 112) {
        // ---- mask convert ----
        int i = bid * 256 + tid;
        int mode = flags[0] ? 0 : (flags[1] ? 1 : 2);
        unsigned char v;
        if (mode == 0)      v = msrc[i] ? 1 : 0;
        else if (mode == 1) v = ((const int*)msrc)[i] ? 1 : 0;
        else                v = ((const long long*)msrc)[i] ? 1 : 0;
        mu8[i] = v;
    } else if (bid < 224) {
        // ---- expand maps ----
        int i = (bid - 112) * 256 + tid;
        if (i < 32*128) { int b = i >> 7; int t2 = i & 127; qmap[i] = b*1024 + qidx[t2]; }
        if (i < 32*896) { int b = i / 896; int t2 = i - b*896; krmap[i] = b*1024 + kmap[t2]; }
    } else {
        // ---- cont path: BN-normalize + 8x256 GEMV + LN + leaky ----
        #pragma unroll
        for (int d = 0; d < 8; ++d) Ws[d][tid] = W[d*256 + tid];
        if (tid < 8) {
            float mean = stats[tid] * (1.0f/32768.0f);
            float var  = stats[8+tid] * (1.0f/32768.0f) - mean*mean;
            float r = rsqrtf(var + EPSV);
            float sc = r * bn_g[tid];
            sscale[tid] = sc;
            sshift[tid] = bn_b[tid] - mean*sc;
        }
        __syncthreads();
        int lane = tid & 63, wv = tid >> 6;
        float gv = g[tid], bv = bL[tid], biasv = bias[tid];
        for (int row = bid - 224; row < 32768; row += 2048) {
            if (tid < 8) cr[tid] = contp[(size_t)row*8 + tid]*sscale[tid] + sshift[tid];
            __syncthreads();
            float acc = biasv;
            #pragma unroll
            for (int d = 0; d < 8; ++d) acc += cr[d]*Ws[d][tid];
            float s = acc;
            #pragma unroll
            for (int o = 32; o; o >>= 1) s += __shfl_xor(s, o);
            if (lane == 0) red[wv] = s;
            __syncthreads();
            float mu = (red[0]+red[1]+red[2]+red[3]) * (1.0f/256.0f);
            float dc = acc - mu;
            float qv = dc*dc;
            #pragma unroll
            for (int o = 32; o; o >>= 1) qv += __shfl_xor(qv, o);
            if (lane == 0) red[4+wv] = qv;
            __syncthreads();
            float var = (red[4]+red[5]+red[6]+red[7]) * (1.0f/256.0f);
            float y = dc * rsqrtf(var + EPSV) * gv + bv;
            y = (y >= 0.f) ? y : 0.01f*y;
            seq3[(size_t)row*768 + 512 + tid] = f2bf(y);
            __syncthreads();
        }
    }
}

// ===========================================================================
// Merged node+cate GEMM+LN+leaky. BM=64, BK=64, 1024 blocks x 512 threads.
// 8 waves (2M x 4N). Phase-fixed schedule (r21 best): loads issued BEFORE
// comp so the compute phase covers their latency; drain-all barrier.
// ===========================================================================
__global__ __launch_bounds__(512, 4) void gemm_nc_k(
    const float* __restrict__ node, const int* __restrict__ cate,
    const float* __restrict__ table,
    const unsigned short* __restrict__ nWt, const unsigned short* __restrict__ cWt,
    const float* __restrict__ nb, const float* __restrict__ cb,
    const float* __restrict__ nlg, const float* __restrict__ nlb,
    const float* __restrict__ clg, const float* __restrict__ clb,
    unsigned short* __restrict__ Y)   // seq3bf, ld 768
{
    __shared__ union UN {
        unsigned short A[2][4096];
        struct { float S[64][4]; float Q[64][4]; } red;
    } U;
    __shared__ unsigned short Bs[2][16384];
    const int t = threadIdx.x;
    const bool isC = blockIdx.x >= 512;
    const int bm = (isC ? (int)blockIdx.x - 512 : (int)blockIdx.x) * 64;
    const int w = t >> 6, l = t & 63, lr = l & 15, lg = l >> 4;
    const int wm = w >> 2, wn = w & 3;
    const int ar = t >> 3;             // 0..63
    const int ac = (t & 7) * 8;        // 8 fp32 per thread per step
    const int aw = ((ac >> 5) << 11) + ((ar >> 4) << 9)
                 + (((ac >> 3) & 3) << 7) + ((ar & 15) << 3);

    const unsigned short* Bc = isC ? cWt : nWt;
    const float* bias = isC ? cb : nb;
    const float* lng  = isC ? clg : nlg;
    const float* lnbp = isC ? clb : nlb;
    const int colOff = isC ? 256 : 0;

    const float* apf = node + (size_t)(bm + ar) * 1024 + ac;
    int4 idx4 = {0,0,0,0};
    if (isC) idx4 = *(const int4*)&cate[(bm + ar) * 4];

    float4v acc[2][4];
    #pragma unroll
    for (int i = 0; i < 2; ++i)
        #pragma unroll
        for (int j = 0; j < 4; ++j) acc[i][j] = (float4v)0.f;

    float4 rA0, rA1;

    auto loadA = [&](int s) {
        const float* p;
        if (isC) {
            int kt = s * 64 + ac;
            int g = kt >> 8;
            int idx = (g == 0) ? idx4.x : (g == 1) ? idx4.y : (g == 2) ? idx4.z : idx4.w;
            p = table + (size_t)idx * 256 + (kt & 255);
        } else {
            p = apf + s * 64;
        }
        rA0 = *(const float4*)p;
        rA1 = *(const float4*)(p + 4);
    };
    auto writeA = [&](unsigned short* Ab) {
        short8v v;
        v[0] = (short)f2bf(rA0.x); v[1] = (short)f2bf(rA0.y);
        v[2] = (short)f2bf(rA0.z); v[3] = (short)f2bf(rA0.w);
        v[4] = (short)f2bf(rA1.x); v[5] = (short)f2bf(rA1.y);
        v[6] = (short)f2bf(rA1.z); v[7] = (short)f2bf(rA1.w);
        *(short8v*)&Ab[aw] = v;
    };
    auto comp = [&](const unsigned short* Ab, const unsigned short* bsb) {
        #pragma unroll
        for (int kk = 0; kk < 2; ++kk) {
            short8v af[2], bf[4];
            #pragma unroll
            for (int i = 0; i < 2; ++i)
                af[i] = *(const short8v*)&Ab[kk*2048 + ((wm*2 + i) << 9) + (lg << 7) + (lr << 3)];
            #pragma unroll
            for (int j = 0; j < 4; ++j)
                bf[j] = *(const short8v*)&bsb[kk*8192 + ((wn*4 + j) << 9) + (lg << 7) + (lr << 3)];
            #pragma unroll
            for (int i = 0; i < 2; ++i)
                #pragma unroll
                for (int j = 0; j < 4; ++j)
                    acc[i][j] = __builtin_amdgcn_mfma_f32_16x16x32_bf16(af[i], bf[j], acc[i][j], 0, 0, 0);
        }
    };

    // prologue: fill A[0] + B[0], drain, barrier
    issue_b8(Bc, 0, &Bs[0][0], w, l);
    loadA(0);
    writeA(U.A[0]);
    VMCNT_BAR(0);

    for (int s = 0; s < 16; ++s) {
        const int cur = s & 1;
        if (s + 1 < 16) {
            issue_b8(Bc, s + 1, &Bs[1 - cur][0], w, l);   // B(s+1): covered by comp
            loadA(s + 1);                                  // A(s+1): covered by comp
        }
        __builtin_amdgcn_sched_barrier(0);                 // pin loads above comp
        comp(U.A[cur], &Bs[cur][0]);
        if (s + 1 < 16) {
            writeA(U.A[1 - cur]);                          // auto-waits A(s+1) (covered)
            VMCNT_BAR(0);                                  // drains B(s+1) (covered)
        }
    }

    // ---- fused LN + leaky epilogue (per-wave 32x64 sub-tile) ----
    #pragma unroll
    for (int j = 0; j < 4; ++j) {
        float bvj = bias[wn*64 + j*16 + lr];
        #pragma unroll
        for (int i = 0; i < 2; ++i)
            #pragma unroll
            for (int r4 = 0; r4 < 4; ++r4) acc[i][j][r4] += bvj;
    }
    __syncthreads();
    #pragma unroll
    for (int i = 0; i < 2; ++i) {
        float ps[4], qs[4];
        #pragma unroll
        for (int r4 = 0; r4 < 4; ++r4) {
            float a0 = acc[i][0][r4], a1 = acc[i][1][r4],
                  a2 = acc[i][2][r4], a3 = acc[i][3][r4];
            ps[r4] = (a0 + a1) + (a2 + a3);
            qs[r4] = (a0*a0 + a1*a1) + (a2*a2 + a3*a3);
        }
        #pragma unroll
        for (int o = 1; o < 16; o <<= 1)
            #pragma unroll
            for (int r4 = 0; r4 < 4; ++r4) {
                ps[r4] += __shfl_xor(ps[r4], o);
                qs[r4] += __shfl_xor(qs[r4], o);
            }
        if (lr == 0) {
            #pragma unroll
            for (int r4 = 0; r4 < 4; ++r4) {
                int rlc = wm*32 + i*16 + lg*4 + r4;
                U.red.S[rlc][wn] = ps[r4];
                U.red.Q[rlc][wn] = qs[r4];
            }
        }
    }
    __syncthreads();
    #pragma unroll
    for (int i = 0; i < 2; ++i) {
        float mu[4], rstd[4];
        #pragma unroll
        for (int r4 = 0; r4 < 4; ++r4) {
            int rlc = wm*32 + i*16 + lg*4 + r4;
            float s  = (U.red.S[rlc][0] + U.red.S[rlc][1]) + (U.red.S[rlc][2] + U.red.S[rlc][3]);
            float qq = (U.red.Q[rlc][0] + U.red.Q[rlc][1]) + (U.red.Q[rlc][2] + U.red.Q[rlc][3]);
            float m_ = s * (1.0f/256.0f);
            mu[r4] = m_;
            rstd[r4] = rsqrtf(qq * (1.0f/256.0f) - m_*m_ + EPSV);
        }
        #pragma unroll
        for (int j = 0; j < 4; ++j) {
            int c = wn*64 + j*16 + lr;
            float gv = lng[c], b2 = lnbp[c];
            #pragma unroll
            for (int r4 = 0; r4 < 4; ++r4) {
                int row = bm + wm*32 + i*16 + lg*4 + r4;
                float y = (acc[i][j][r4] - mu[r4]) * rstd[r4] * gv + b2;
                y = (y >= 0.f) ? y : 0.01f*y;
                Y[(size_t)row * 768 + colOff + c] = f2bf(y);
            }
        }
    }
}

// ===========================================================================
// comb GEMM+LN+pos: 8-wave template, phase-fixed schedule. BM=64, BK=64,
// 512 blocks x 512 threads, 12 steps, A bf16 [32768][768].
// ===========================================================================
__global__ __launch_bounds__(512, 4) void gemm_comb_k(
    const unsigned short* __restrict__ A,
    const unsigned short* __restrict__ Bc,
    const float* __restrict__ bias,
    const float* __restrict__ lng, const float* __restrict__ lnbp,
    const float* __restrict__ pos,
    unsigned short* __restrict__ Y)          // seqbf [32768][256]
{
    __shared__ union UC {
        unsigned short A[2][4096];
        struct { float S[64][4]; float Q[64][4]; } red;
    } U;
    __shared__ unsigned short Bs[2][16384];
    const int t = threadIdx.x;
    const int bm = blockIdx.x * 64;
    const int w = t >> 6, l = t & 63, lr = l & 15, lg = l >> 4;
    const int wm = w >> 2, wn = w & 3;
    const int ar = t >> 3;
    const int ak = (t & 7) * 8;
    const int aw = ((ak >> 5) << 11) + ((ar >> 4) << 9)
                 + (((ak >> 3) & 3) << 7) + ((ar & 15) << 3);

    const unsigned short* ap = A + (size_t)(bm + ar) * 768 + ak;

    float4v acc[2][4];
    #pragma unroll
    for (int i = 0; i < 2; ++i)
        #pragma unroll
        for (int j = 0; j < 4; ++j) acc[i][j] = (float4v)0.f;

    short8v aA;

    auto comp = [&](const unsigned short* Ab, const unsigned short* bsb) {
        #pragma unroll
        for (int kk = 0; kk < 2; ++kk) {
            short8v af[2], bf[4];
            #pragma unroll
            for (int i = 0; i < 2; ++i)
                af[i] = *(const short8v*)&Ab[kk*2048 + ((wm*2 + i) << 9) + (lg << 7) + (lr << 3)];
            #pragma unroll
            for (int j = 0; j < 4; ++j)
                bf[j] = *(const short8v*)&bsb[kk*8192 + ((wn*4 + j) << 9) + (lg << 7) + (lr << 3)];
            #pragma unroll
            for (int i = 0; i < 2; ++i)
                #pragma unroll
                for (int j = 0; j < 4; ++j)
                    acc[i][j] = __builtin_amdgcn_mfma_f32_16x16x32_bf16(af[i], bf[j], acc[i][j], 0, 0, 0);
        }
    };

    issue_b8(Bc, 0, &Bs[0][0], w, l);
    aA = *(const short8v*)(ap);
    *(short8v*)&U.A[0][aw] = aA;
    VMCNT_BAR(0);

    for (int s = 0; s < 12; ++s) {
        const int cur = s & 1;
        if (s + 1 < 12) {
            issue_b8(Bc, s + 1, &Bs[1 - cur][0], w, l);
            aA = *(const short8v*)(ap + (s + 1) * 64);
        }
        __builtin_amdgcn_sched_barrier(0);
        comp(U.A[cur], &Bs[cur][0]);
        if (s + 1 < 12) {
            *(short8v*)&U.A[1 - cur][aw] = aA;
            VMCNT_BAR(0);
        }
    }

    // ---- fused LN + pos epilogue (per-wave 32x64 sub-tile) ----
    #pragma unroll
    for (int j = 0; j < 4; ++j) {
        float bvj = bias[wn*64 + j*16 + lr];
        #pragma unroll
        for (int i = 0; i < 2; ++i)
            #pragma unroll
            for (int r4 = 0; r4 < 4; ++r4) acc[i][j][r4] += bvj;
    }
    __syncthreads();
    #pragma unroll
    for (int i = 0; i < 2; ++i) {
        float ps[4], qs[4];
        #pragma unroll
        for (int r4 = 0; r4 < 4; ++r4) {
            float a0 = acc[i][0][r4], a1 = acc[i][1][r4],
                  a2 = acc[i][2][r4], a3 = acc[i][3][r4];
            ps[r4] = (a0 + a1) + (a2 + a3);
            qs[r4] = (a0*a0 + a1*a1) + (a2*a2 + a3*a3);
        }
        #pragma unroll
        for (int o = 1; o < 16; o <<= 1)
            #pragma unroll
            for (int r4 = 0; r4 < 4; ++r4) {
                ps[r4] += __shfl_xor(ps[r4], o);
                qs[r4] += __shfl_xor(qs[r4], o);
            }
        if (lr == 0) {
            #pragma unroll
            for (int r4 = 0; r4 < 4; ++r4) {
                int rlc = wm*32 + i*16 + lg*4 + r4;
                U.red.S[rlc][wn] = ps[r4];
                U.red.Q[rlc][wn] = qs[r4];
            }
        }
    }
    __syncthreads();
    #pragma unroll
    for (int i = 0; i < 2; ++i) {
        float mu[4], rstd[4];
        #pragma unroll
        for (int r4 = 0; r4 < 4; ++r4) {
            int rlc = wm*32 + i*16 + lg*4 + r4;
            float s  = (U.red.S[rlc][0] + U.red.S[rlc][1]) + (U.red.S[rlc][2] + U.red.S[rlc][3]);
            float qq = (U.red.Q[rlc][0] + U.red.Q[rlc][1]) + (U.red.Q[rlc][2] + U.red.Q[rlc][3]);
            float m_ = s * (1.0f/256.0f);
            mu[r4] = m_;
            rstd[r4] = rsqrtf(qq * (1.0f/256.0f) - m_*m_ + EPSV);
        }
        #pragma unroll
        for (int j = 0; j < 4; ++j) {
            int c = wn*64 + j*16 + lr;
            float gv = lng[c], b2 = lnbp[c];
            #pragma unroll
            for (int r4 = 0; r4 < 4; ++r4) {
                int row = bm + wm*32 + i*16 + lg*4 + r4;
                float y = (acc[i][j][r4] - mu[r4]) * rstd[r4] * gv + b2
                        + pos[(size_t)(row & 1023) * 256 + c];
                Y[(size_t)row * 256 + c] = f2bf(y);
            }
        }
    }
}

// ===========================================================================
// Merged Q/K/V projections, BM=64, BK=64: 960 blocks x 512 threads, 8 waves.
// Phase-fixed schedule.
// ===========================================================================
__global__ __launch_bounds__(512, 4) void gemm_qkv_k(
    const unsigned short* __restrict__ seq,
    const int* __restrict__ qmap, const int* __restrict__ krmap,
    const unsigned short* __restrict__ qWt, const unsigned short* __restrict__ kWt,
    const unsigned short* __restrict__ vWt,
    const float* __restrict__ qb, const float* __restrict__ kb, const float* __restrict__ vb,
    unsigned short* __restrict__ Qo, unsigned short* __restrict__ Ko,
    unsigned short* __restrict__ Vt)
{
    __shared__ unsigned short Asl[2][4096];
    __shared__ unsigned short Bs[2][16384];
    const int t = threadIdx.x;
    const int bid = blockIdx.x;
    int seg, bm;
    const int* gmap; const unsigned short* Bc; const float* bias;
    if (bid < 64)       { seg = 0; bm = bid * 64;         gmap = qmap;  Bc = qWt; bias = qb; }
    else if (bid < 512) { seg = 1; bm = (bid - 64) * 64;  gmap = krmap; Bc = kWt; bias = kb; }
    else                { seg = 2; bm = (bid - 512) * 64; gmap = krmap; Bc = vWt; bias = vb; }
    const int w = t >> 6, l = t & 63, lr = l & 15, lg = l >> 4;
    const int wm = w >> 2, wn = w & 3;
    const int ar = t >> 3;
    const int ak = (t & 7) * 8;
    const int aw = ((ak >> 5) << 11) + ((ar >> 4) << 9)
                 + (((ak >> 3) & 3) << 7) + ((ar & 15) << 3);

    const unsigned short* ap = seq + (size_t)gmap[bm + ar] * 256 + ak;

    float4v acc[2][4];
    #pragma unroll
    for (int i = 0; i < 2; ++i)
        #pragma unroll
        for (int j = 0; j < 4; ++j) acc[i][j] = (float4v)0.f;

    short8v aA;

    auto comp = [&](const unsigned short* Ab, const unsigned short* bsb) {
        #pragma unroll
        for (int kk = 0; kk < 2; ++kk) {
            short8v af[2], bf[4];
            #pragma unroll
            for (int i = 0; i < 2; ++i)
                af[i] = *(const short8v*)&Ab[kk*2048 + ((wm*2 + i) << 9) + (lg << 7) + (lr << 3)];
            #pragma unroll
            for (int j = 0; j < 4; ++j)
                bf[j] = *(const short8v*)&bsb[kk*8192 + ((wn*4 + j) << 9) + (lg << 7) + (lr << 3)];
            #pragma unroll
            for (int i = 0; i < 2; ++i)
                #pragma unroll
                for (int j = 0; j < 4; ++j)
                    acc[i][j] = __builtin_amdgcn_mfma_f32_16x16x32_bf16(af[i], bf[j], acc[i][j], 0, 0, 0);
        }
    };

    issue_b8(Bc, 0, &Bs[0][0], w, l);
    aA = *(const short8v*)(ap);
    *(short8v*)&Asl[0][aw] = aA;
    VMCNT_BAR(0);

    for (int s = 0; s < 4; ++s) {
        const int cur = s & 1;
        if (s + 1 < 4) {
            issue_b8(Bc, s + 1, &Bs[1 - cur][0], w, l);
            aA = *(const short8v*)(ap + (s + 1) * 64);
        }
        __builtin_amdgcn_sched_barrier(0);
        comp(Asl[cur], &Bs[cur][0]);
        if (s + 1 < 4) {
            *(short8v*)&Asl[1 - cur][aw] = aA;
            VMCNT_BAR(0);
        }
    }

    unsigned short* outp = (seg == 0) ? Qo : (seg == 1) ? Ko : Vt;
    #pragma unroll
    for (int j = 0; j < 4; ++j) {
        int c = wn*64 + j*16 + lr;
        float bvj = bias[c];
        #pragma unroll
        for (int i = 0; i < 2; ++i) {
            #pragma unroll
            for (int r4 = 0; r4 < 4; ++r4) {
                int rl = wm*32 + i*16 + lg*4 + r4;
                float val = acc[i][j][r4] + bvj;
                if (seg < 2) {
                    outp[(size_t)(bm + rl) * 256 + c] = f2bf(val);
                } else {
                    int vbk = bm / 896;
                    int kl = bm - vbk * 896 + rl;
                    outp[((size_t)vbk * 256 + c) * 896 + kl] = f2bf(val);
                }
            }
        }
    }
}

// ---------------------------------------------------------------------------
// Regression-head GEMM (BM=64, BK=64, K=256, 256 thr). EPI: 0 f32; 3 LN+leaky.
// ---------------------------------------------------------------------------
template<int EPI>
__global__ __launch_bounds__(256) void gemm_reg_k(
    const unsigned short* __restrict__ Asrc,
    const unsigned short* __restrict__ Bc,
    const float* __restrict__ bias,
    const float* __restrict__ ln_g,
    const float* __restrict__ ln_b,
    void* __restrict__ Cout)
{
    __shared__ union UR {
        unsigned short A[2][4096];
        struct { float S[64][4]; float Q[64][4]; } red;
    } U;
    __shared__ unsigned short Bs[2][16384];
    const int t = threadIdx.x;
    const int bm = blockIdx.x * 64;
    const int w = t >> 6, l = t & 63, lr = l & 15, lg = l >> 4;
    const int ar = t >> 2;
    const int ac = (t & 3) * 16;
    const int aw0 = (((t & 3) >> 1) << 11) + ((ar >> 4) << 9)
                  + ((((t & 3) * 2) & 3) << 7) + ((ar & 15) << 3);
    const int aw1 = aw0 + 128;

    const unsigned short* ap = Asrc + (size_t)(bm + ar) * 256 + ac;

    float4v acc[4][4];
    #pragma unroll
    for (int i = 0; i < 4; ++i)
        #pragma unroll
        for (int j = 0; j < 4; ++j) acc[i][j] = (float4v)0.f;

    short8v a0A, a1A, a0B, a1B;

    auto comp = [&](const unsigned short* Ab, const unsigned short* bsb) {
        #pragma unroll
        for (int kk = 0; kk < 2; ++kk) {
            short8v af[4], bf[4];
            #pragma unroll
            for (int i = 0; i < 4; ++i)
                af[i] = *(const short8v*)&Ab[kk*2048 + i*512 + lg*128 + lr*8];
            #pragma unroll
            for (int j = 0; j < 4; ++j)
                bf[j] = *(const short8v*)&bsb[kk*8192 + ((w*4 + j) << 9) + (lg << 7) + (lr << 3)];
            #pragma unroll
            for (int i = 0; i < 4; ++i)
                #pragma unroll
                for (int j = 0; j < 4; ++j)
                    acc[i][j] = __builtin_amdgcn_mfma_f32_16x16x32_bf16(af[i], bf[j], acc[i][j], 0, 0, 0);
        }
    };

    issue_b(Bc, 0, &Bs[0][0], w, l);
    issue_b(Bc, 1, &Bs[0][8192], w, l);
    a0A = *(const short8v*)(ap);
    a1A = *(const short8v*)(ap + 8);
    for (int s = 0; s < 4; ++s) {
        int cur = s & 1;
        __syncthreads();
        *(short8v*)&U.A[cur][aw0] = a0A;
        *(short8v*)&U.A[cur][aw1] = a1A;
        __syncthreads();
        if (s + 1 < 4) {
            issue_b(Bc, 2*(s+1),     &Bs[1 - cur][0],    w, l);
            issue_b(Bc, 2*(s+1) + 1, &Bs[1 - cur][8192], w, l);
            a0B = *(const short8v*)(ap + (s + 1) * 64);
            a1B = *(const short8v*)(ap + (s + 1) * 64 + 8);
        }
        comp(U.A[cur], &Bs[cur][0]);
        a0A = a0B; a1A = a1B;
    }

    #pragma unroll
    for (int j = 0; j < 4; ++j) {
        float bvj = bias[w*64 + j*16 + lr];
        #pragma unroll
        for (int i = 0; i < 4; ++i)
            #pragma unroll
            for (int r4 = 0; r4 < 4; ++r4) acc[i][j][r4] += bvj;
    }

    if (EPI == 0) {
        #pragma unroll
        for (int i = 0; i < 4; ++i)
            #pragma unroll
            for (int j = 0; j < 4; ++j) {
                int c = w*64 + j*16 + lr;
                #pragma unroll
                for (int r4 = 0; r4 < 4; ++r4) {
                    int rl = i*16 + lg*4 + r4;
                    ((float*)Cout)[(size_t)(bm + rl) * 256 + c] = acc[i][j][r4];
                }
            }
    } else {
        __syncthreads();
        #pragma unroll
        for (int i = 0; i < 4; ++i) {
            float ps[4], qs[4];
            #pragma unroll
            for (int r4 = 0; r4 < 4; ++r4) {
                float a0 = acc[i][0][r4], a1 = acc[i][1][r4],
                      a2 = acc[i][2][r4], a3 = acc[i][3][r4];
                ps[r4] = (a0 + a1) + (a2 + a3);
                qs[r4] = (a0*a0 + a1*a1) + (a2*a2 + a3*a3);
            }
            #pragma unroll
            for (int o = 1; o < 16; o <<= 1)
                #pragma unroll
                for (int r4 = 0; r4 < 4; ++r4) {
                    ps[r4] += __shfl_xor(ps[r4], o);
                    qs[r4] += __shfl_xor(qs[r4], o);
                }
            if (lr == 0) {
                #pragma unroll
                for (int r4 = 0; r4 < 4; ++r4) {
                    U.red.S[i*16 + lg*4 + r4][w] = ps[r4];
                    U.red.Q[i*16 + lg*4 + r4][w] = qs[r4];
                }
            }
        }
        __syncthreads();
        #pragma unroll
        for (int i = 0; i < 4; ++i) {
            float mu[4], rstd[4];
            #pragma unroll
            for (int r4 = 0; r4 < 4; ++r4) {
                int rl = i*16 + lg*4 + r4;
                float s  = (U.red.S[rl][0] + U.red.S[rl][1]) + (U.red.S[rl][2] + U.red.S[rl][3]);
                float qq = (U.red.Q[rl][0] + U.red.Q[rl][1]) + (U.red.Q[rl][2] + U.red.Q[rl][3]);
                float m_ = s * (1.0f/256.0f);
                mu[r4] = m_;
                rstd[r4] = rsqrtf(qq * (1.0f/256.0f) - m_*m_ + EPSV);
            }
            #pragma unroll
            for (int j = 0; j < 4; ++j) {
                int c = w*64 + j*16 + lr;
                float gv = ln_g[c], b2 = ln_b[c];
                #pragma unroll
                for (int r4 = 0; r4 < 4; ++r4) {
                    int row = bm + i*16 + lg*4 + r4;
                    float y = (acc[i][j][r4] - mu[r4]) * rstd[r4] * gv + b2;
                    y = (y >= 0.f) ? y : 0.01f*y;
                    ((unsigned short*)Cout)[(size_t)row * 256 + c] = f2bf(y);
                }
            }
        }
    }
}

// ---------------------------------------------------------------------------
// MFMA flash attention. Grid 512 = (b, h, qhalf). 4 waves/block.
// ---------------------------------------------------------------------------
__global__ __launch_bounds__(256) void attn_mfma_k(
    const unsigned short* __restrict__ Qb,
    const unsigned short* __restrict__ Kb,
    const unsigned short* __restrict__ Vtb,
    const unsigned char* __restrict__ mask,
    unsigned short* __restrict__ out)
{
    __shared__ unsigned short Pw[4][16][72];
    const int t = threadIdx.x;
    const int w = t >> 6, l = t & 63;
    const int lr = l & 15, lg = l >> 4;
    const int bx = blockIdx.x;
    const int qh = bx & 1, h = (bx >> 1) & 7, b = bx >> 4;
    const int qrow0 = b*128 + qh*64 + w*16;

    short8v qf = *(const short8v*)&Qb[(size_t)(qrow0 + lr)*256 + h*32 + lg*8];

    const unsigned short* Kbase = Kb + (size_t)b*896*256 + h*32;
    const unsigned short* Vbase = Vtb + ((size_t)b*256 + h*32)*896;
    const unsigned char* mrow = mask + b*896;

    float4v O0 = (float4v)0.f, O1 = (float4v)0.f;
    float m[4], lsum[4];
    #pragma unroll
    for (int r = 0; r < 4; ++r) { m[r] = -3.0e38f; lsum[r] = 0.f; }

    short8v kf[4], vf[4];
    int mk[4];
    #pragma unroll
    for (int i = 0; i < 4; ++i) {
        kf[i] = *(const short8v*)&Kbase[(size_t)(i*16 + lr)*256 + lg*8];
        mk[i] = mrow[i*16 + lr];
    }
    #pragma unroll
    for (int kc = 0; kc < 2; ++kc)
        #pragma unroll
        for (int nt = 0; nt < 2; ++nt)
            vf[kc*2+nt] = *(const short8v*)&Vbase[(size_t)(nt*16 + lr)*896 + kc*32 + lg*8];

    for (int kt3 = 0; kt3 < 14; ++kt3) {
        const int kb2 = kt3*64 + 64;
        short8v kf2[4], vf2[4];
        int mk2[4];
        if (kt3 < 13) {
            #pragma unroll
            for (int i = 0; i < 4; ++i) {
                kf2[i] = *(const short8v*)&Kbase[(size_t)(kb2 + i*16 + lr)*256 + lg*8];
                mk2[i] = mrow[kb2 + i*16 + lr];
            }
            #pragma unroll
            for (int kc = 0; kc < 2; ++kc)
                #pragma unroll
                for (int nt = 0; nt < 2; ++nt)
                    vf2[kc*2+nt] = *(const short8v*)&Vbase[(size_t)(nt*16 + lr)*896 + kb2 + kc*32 + lg*8];
        }
        float4v s4[4];
        #pragma unroll
        for (int i = 0; i < 4; ++i)
            s4[i] = __builtin_amdgcn_mfma_f32_16x16x32_bf16(qf, kf[i], (float4v)0.f, 0, 0, 0);
        #pragma unroll
        for (int i = 0; i < 4; ++i)
            #pragma unroll
            for (int r = 0; r < 4; ++r)
                s4[i][r] = mk[i] ? -1e9f : s4[i][r] * 0.17677669529663687f;
        float tm[4];
        #pragma unroll
        for (int r = 0; r < 4; ++r)
            tm[r] = fmaxf(fmaxf(s4[0][r], s4[1][r]), fmaxf(s4[2][r], s4[3][r]));
        #pragma unroll
        for (int o = 1; o < 16; o <<= 1)
            #pragma unroll
            for (int r = 0; r < 4; ++r) tm[r] = fmaxf(tm[r], __shfl_xor(tm[r], o));
        float resc[4];
        #pragma unroll
        for (int r = 0; r < 4; ++r) {
            float mn = fmaxf(m[r], tm[r]);
            resc[r] = __expf(m[r] - mn);
            m[r] = mn;
        }
        float rs[4] = {0.f, 0.f, 0.f, 0.f};
        #pragma unroll
        for (int i = 0; i < 4; ++i)
            #pragma unroll
            for (int r = 0; r < 4; ++r) {
                float p = __expf(s4[i][r] - m[r]);
                s4[i][r] = p;
                rs[r] += p;
            }
        #pragma unroll
        for (int o = 1; o < 16; o <<= 1)
            #pragma unroll
            for (int r = 0; r < 4; ++r) rs[r] += __shfl_xor(rs[r], o);
        #pragma unroll
        for (int r = 0; r < 4; ++r) lsum[r] = lsum[r]*resc[r] + rs[r];
        #pragma unroll
        for (int r = 0; r < 4; ++r) { O0[r] *= resc[r]; O1[r] *= resc[r]; }
        #pragma unroll
        for (int i = 0; i < 4; ++i)
            #pragma unroll
            for (int r = 0; r < 4; ++r)
                Pw[w][lg*4 + r][i*16 + lr] = f2bf(s4[i][r]);
        #pragma unroll
        for (int kc = 0; kc < 2; ++kc) {
            short8v pf = *(const short8v*)&Pw[w][lr][kc*32 + lg*8];
            O0 = __builtin_amdgcn_mfma_f32_16x16x32_bf16(pf, vf[kc*2+0], O0, 0, 0, 0);
            O1 = __builtin_amdgcn_mfma_f32_16x16x32_bf16(pf, vf[kc*2+1], O1, 0, 0, 0);
        }
        if (kt3 < 13) {
            #pragma unroll
            for (int i = 0; i < 4; ++i) { kf[i] = kf2[i]; mk[i] = mk2[i]; vf[i] = vf2[i]; }
        }
    }
    #pragma unroll
    for (int r = 0; r < 4; ++r) {
        float inv = 1.0f / lsum[r];
        size_t row = (size_t)(qrow0 + lg*4 + r);
        out[row*256 + h*32 + lr]      = f2bf(O0[r] * inv);
        out[row*256 + h*32 + 16 + lr] = f2bf(O1[r] * inv);
    }
}

// ---------------------------------------------------------------------------
extern "C" void kernel_launch(void* const* d_in, const int* in_sizes, int n_in,
                              void* d_out, int out_size, void* d_ws, size_t ws_size,
                              hipStream_t stream)
{
    const float* node       = (const float*)d_in[0];
    const int*   cate       = (const int*)d_in[1];
    const float* cont       = (const float*)d_in[2];
    const int*   qidx       = (const int*)d_in[3];
    const unsigned char* mask = (const unsigned char*)d_in[4];
    const float* cate_table = (const float*)d_in[5];
    const float* pos_emb    = (const float*)d_in[6];
    const float* node_W     = (const float*)d_in[7];
    const float* node_b     = (const float*)d_in[8];
    const float* node_ln_g  = (const float*)d_in[9];
    const float* node_ln_b  = (const float*)d_in[10];
    const float* cate_W     = (const float*)d_in[11];
    const float* cate_b     = (const float*)d_in[12];
    const float* cate_ln_g  = (const float*)d_in[13];
    const float* cate_ln_b  = (const float*)d_in[14];
    const float* bn_g       = (const float*)d_in[15];
    const float* bn_b       = (const float*)d_in[16];
    const float* cont_W     = (const float*)d_in[17];
    const float* cont_b     = (const float*)d_in[18];
    const float* cont_ln_g  = (const float*)d_in[19];
    const float* cont_ln_b  = (const float*)d_in[20];
    const float* comb_W     = (const float*)d_in[21];
    const float* comb_b     = (const float*)d_in[22];
    const float* comb_ln_g  = (const float*)d_in[23];
    const float* comb_ln_b  = (const float*)d_in[24];
    const float* q_W        = (const float*)d_in[25];
    const float* q_b        = (const float*)d_in[26];
    const float* k_W        = (const float*)d_in[27];
    const float* k_b        = (const float*)d_in[28];
    const float* v_W        = (const float*)d_in[29];
    const float* v_b        = (const float*)d_in[30];
    const float* reg_W1     = (const float*)d_in[31];
    const float* reg_b1     = (const float*)d_in[32];
    const float* reg_ln_g   = (const float*)d_in[33];
    const float* reg_ln_b   = (const float*)d_in[34];
    const float* reg_W2     = (const float*)d_in[35];
    const float* reg_b2     = (const float*)d_in[36];

    char* ws = (char*)d_ws;
    unsigned short* seq3bf = (unsigned short*)(ws + 0);          // 32768*768*2
    unsigned short* seqbf  = (unsigned short*)(ws + 83886080);   // 32768*256*2
    unsigned short* Qbf    = (unsigned short*)(ws + 100663296);
    unsigned short* Kbf    = (unsigned short*)(ws + 102760448);
    unsigned short* Vtbf   = (unsigned short*)(ws + 117440512);
    unsigned short* AObf   = (unsigned short*)(ws + 132120576);
    unsigned short* Hbf    = (unsigned short*)(ws + 0);          // reuse seq3bf region
    float* stats = (float*)(ws + 165675008);
    int*   flags = (int*)  (ws + 165675072);
    int*   kmap  = (int*)  (ws + 165675136);
    int*   qmap  = (int*)  (ws + 165678720);
    int*   krmap = (int*)  (ws + 165695104);
    unsigned char* mu8 = (unsigned char*)(ws + 165809792);
    unsigned short* node_Wt = (unsigned short*)(ws + 165838464);
    unsigned short* cate_Wt = (unsigned short*)(ws + 166362752);
    unsigned short* comb_Wt = (unsigned short*)(ws + 166887040);
    unsigned short* q_Wt    = (unsigned short*)(ws + 167280256);
    unsigned short* k_Wt    = (unsigned short*)(ws + 167411328);
    unsigned short* v_Wt    = (unsigned short*)(ws + 167542400);
    unsigned short* r1_Wt   = (unsigned short*)(ws + 167673472);
    unsigned short* r2_Wt   = (unsigned short*)(ws + 167804544);
    float* outp = (float*)d_out;

    hipMemsetAsync(stats, 0, 128, stream);
    // prep1: wt_all + bn_stats + mask_sniff + build_maps (625 blocks)
    prep1_k<<<625, 256, 0, stream>>>(cont, stats, mask, flags, qidx, kmap,
        node_W, cate_W, comb_W, q_W, k_W, v_W, reg_W1, reg_W2,
        node_Wt, cate_Wt, comb_Wt, q_Wt, k_Wt, v_Wt, r1_Wt, r2_Wt);
    // prep2: mask_conv + expand_maps + cont path (2272 blocks)
    prep2_k<<<2272, 256, 0, stream>>>(mask, flags, mu8, qidx, kmap, qmap, krmap,
        cont, stats, bn_g, bn_b, cont_W, cont_b, cont_ln_g, cont_ln_b, seq3bf);
    // node + cate (merged, BM=64/BK=64, 8-wave, phase-fixed: 1024 x 512)
    gemm_nc_k<<<1024, 512, 0, stream>>>(node, cate, cate_table, node_Wt, cate_Wt,
        node_b, cate_b, node_ln_g, node_ln_b, cate_ln_g, cate_ln_b, seq3bf);
    // comb (8-wave, phase-fixed: 512 x 512)
    gemm_comb_k<<<512, 512, 0, stream>>>(seq3bf, comb_Wt, comb_b,
        comb_ln_g, comb_ln_b, pos_emb, seqbf);
    // Q/K/V merged (8-wave, phase-fixed: 960 x 512)
    gemm_qkv_k<<<960, 512, 0, stream>>>(seqbf, qmap, krmap, q_Wt, k_Wt, v_Wt,
        q_b, k_b, v_b, Qbf, Kbf, Vtbf);
    // attention
    attn_mfma_k<<<512, 256, 0, stream>>>(Qbf, Kbf, Vtbf, mu8, AObf);
    // regression head
    gemm_reg_k<3><<<64, 256, 0, stream>>>(AObf, r1_Wt, reg_b1, reg_ln_g, reg_ln_b, Hbf);
    gemm_reg_k<0><<<64, 256, 0, stream>>>(Hbf, r2_Wt, reg_b2, nullptr, nullptr, outp);
}